// Round 4
// baseline (17447.266 us; speedup 1.0000x reference)
//
#include <hip/hip_runtime.h>
#include <math.h>

#define Dh 1024
#define Tt 4096
#define NB 128   // recurrence blocks; each owns 8 output columns

// ---------------------------------------------------------------------------
// GEMM: C[M x N](ldc) = op(A[M x K]) @ B[K x N] + bias [+ resid]
// 64x64 tile, BK=16, 256 threads, 4x4 micro-tile per thread. fp32.
// ---------------------------------------------------------------------------
template<bool RELU, bool RESID>
__global__ __launch_bounds__(256)
void gemm64(const float* __restrict__ A, const float* __restrict__ B,
            const float* __restrict__ bias, const float* __restrict__ resid,
            float* __restrict__ C, int M, int N, int K, int ldc)
{
    __shared__ __align__(16) float As[16][68];   // [k][m], padded row
    __shared__ __align__(16) float Bs[16][64];   // [k][n]
    const int tid = threadIdx.x;
    const int tx = tid & 15, ty = tid >> 4;
    const int bn = blockIdx.x * 64, bm = blockIdx.y * 64;

    const int lm = tid >> 2, lk = (tid & 3) * 4;     // A tile load coords
    const int bk = tid >> 4, bn4 = (tid & 15) * 4;   // B tile load coords

    float acc[4][4] = {};

    for (int k0 = 0; k0 < K; k0 += 16) {
        float4 av = *(const float4*)(A + (size_t)(bm + lm) * K + k0 + lk);
        if (RELU) {
            av.x = fmaxf(av.x, 0.f); av.y = fmaxf(av.y, 0.f);
            av.z = fmaxf(av.z, 0.f); av.w = fmaxf(av.w, 0.f);
        }
        As[lk + 0][lm] = av.x; As[lk + 1][lm] = av.y;
        As[lk + 2][lm] = av.z; As[lk + 3][lm] = av.w;
        *(float4*)&Bs[bk][bn4] = *(const float4*)(B + (size_t)(k0 + bk) * N + bn + bn4);
        __syncthreads();
        #pragma unroll
        for (int kk = 0; kk < 16; ++kk) {
            float4 a4 = *(const float4*)&As[kk][ty * 4];
            float4 b4 = *(const float4*)&Bs[kk][tx * 4];
            acc[0][0] += a4.x * b4.x; acc[0][1] += a4.x * b4.y; acc[0][2] += a4.x * b4.z; acc[0][3] += a4.x * b4.w;
            acc[1][0] += a4.y * b4.x; acc[1][1] += a4.y * b4.y; acc[1][2] += a4.y * b4.z; acc[1][3] += a4.y * b4.w;
            acc[2][0] += a4.z * b4.x; acc[2][1] += a4.z * b4.y; acc[2][2] += a4.z * b4.z; acc[2][3] += a4.z * b4.w;
            acc[3][0] += a4.w * b4.x; acc[3][1] += a4.w * b4.y; acc[3][2] += a4.w * b4.z; acc[3][3] += a4.w * b4.w;
        }
        __syncthreads();
    }

    const float4 bias4 = *(const float4*)(bias + bn + tx * 4);
    #pragma unroll
    for (int i = 0; i < 4; ++i) {
        const int row = bm + ty * 4 + i;
        float4 o;
        o.x = acc[i][0] + bias4.x; o.y = acc[i][1] + bias4.y;
        o.z = acc[i][2] + bias4.z; o.w = acc[i][3] + bias4.w;
        if (RESID) {
            const float4 r4 = *(const float4*)(resid + (size_t)row * N + bn + tx * 4);
            o.x += r4.x; o.y += r4.y; o.z += r4.z; o.w += r4.w;
        }
        *(float4*)(C + (size_t)row * ldc + bn + tx * 4) = o;
    }
}

// ---------------------------------------------------------------------------
// Fast activations — tolerance is 0.099 absmax; native exp/rcp are ~1e-6 rel.
// ---------------------------------------------------------------------------
__device__ __forceinline__ float fast_sigmoid(float x)
{
    return __builtin_amdgcn_rcpf(1.f + __expf(-x));
}
__device__ __forceinline__ float fast_tanh(float x)
{
    x = fminf(15.f, fmaxf(-15.f, x));
    const float e2 = __expf(2.f * x);
    return (e2 - 1.f) * __builtin_amdgcn_rcpf(e2 + 1.f);
}

// ---------------------------------------------------------------------------
// Pack init_state into epoch-tagged slots: {tag=0 : value} in buf[0]
// ---------------------------------------------------------------------------
__global__ __launch_bounds__(256)
void pack_h0(const float* __restrict__ h0, unsigned long long* __restrict__ buf)
{
    const int idx = blockIdx.x * 256 + threadIdx.x;   // 0..1023
    __hip_atomic_store(buf + idx, (unsigned long long)__float_as_uint(h0[idx]),
                       __ATOMIC_RELAXED, __HIP_MEMORY_SCOPE_AGENT);
}

// ---------------------------------------------------------------------------
// Sequential GRU scan. 128 blocks x 256 threads, all co-resident.
// Block b owns output columns [8b, 8b+8); each column = one 32-lane group.
// Weights register/AGPR-resident (96 floats/thread).
//
// Sync protocol (anti-poll-storm): producers store tagged {t+1,val} data
// slots AND bump a tiny per-block flag. Consumers poll ONLY the 8-line flag
// array with a single wave (128 blocks x 8 line-reqs per round instead of
// 16K), then bulk-read the 8KB data region ONCE with coalesced 32B/thread
// loads. Tags catch flag-before-data arrival races (rare retry), so all
// atomics stay relaxed — no fences on the critical path.
// ---------------------------------------------------------------------------
__global__ __launch_bounds__(256, 1)
void gru_rec(const float* __restrict__ xproj,   // [T][3*Dh]  (r,z,n) incl. input bias
             const float* __restrict__ Whr, const float* __restrict__ Whz,
             const float* __restrict__ Whn, const float* __restrict__ bhn,
             float* __restrict__ ys,            // [T][Dh]
             unsigned long long* __restrict__ hbuf,   // [2][Dh] packed {tag,val}
             unsigned int* __restrict__ flags)        // [NB] published-step count
{
    const int b = blockIdx.x, tid = threadIdx.x;
    const int g = tid >> 5;        // group 0..7 -> local column
    const int i = tid & 31;        // lane in group
    const int col = b * 8 + g;

    __shared__ __align__(16) float h_lds[Dh];

    // Register-resident weight slice: rows r = 4i + 128j + k
    float wr[32], wz[32], wn[32];
    #pragma unroll
    for (int j = 0; j < 8; ++j)
        #pragma unroll
        for (int k = 0; k < 4; ++k) {
            const int r = 4 * i + 128 * j + k;
            wr[j * 4 + k] = Whr[(size_t)r * Dh + col];
            wz[j * 4 + k] = Whz[(size_t)r * Dh + col];
            wn[j * 4 + k] = Whn[(size_t)r * Dh + col];
        }
    const float bhn_c = bhn[col];

    // xproj prefetch registers (one step ahead)
    float xr_n = 0.f, xz_n = 0.f, xn_n = 0.f;
    if (i == 0) {
        xr_n = xproj[col]; xz_n = xproj[Dh + col]; xn_n = xproj[2 * Dh + col];
    }
    float y_prev = 0.f;

    const unsigned long long* fpair = (const unsigned long long*)flags;

    for (int t = 0; t < Tt; ++t) {
        const unsigned long long* src = hbuf + (size_t)(t & 1) * Dh;
        unsigned long long*       dst = hbuf + (size_t)((t + 1) & 1) * Dh;
        const unsigned int want = (unsigned int)t;

        const float xr = xr_n, xz = xz_n, xn = xn_n;

        // ---- notification: wave 0 polls the 128 flags (8 cache lines) ----
        if (tid < 64) {
            int tries = 0;
            for (;;) {
                const unsigned long long v =
                    __hip_atomic_load(fpair + tid, __ATOMIC_RELAXED, __HIP_MEMORY_SCOPE_AGENT);
                const int ok = ((unsigned int)v >= want) &&
                               ((unsigned int)(v >> 32) >= want);
                if (__all(ok)) break;
                if (++tries > 8) __builtin_amdgcn_s_sleep(1);
            }
        }
        __syncthreads();

        // ---- bulk data read: 4 contiguous slots (32B) per thread, tagged ----
        const int s0 = tid * 4;
        unsigned long long q0, q1, q2, q3;
        for (;;) {
            q0 = __hip_atomic_load(src + s0 + 0, __ATOMIC_RELAXED, __HIP_MEMORY_SCOPE_AGENT);
            q1 = __hip_atomic_load(src + s0 + 1, __ATOMIC_RELAXED, __HIP_MEMORY_SCOPE_AGENT);
            q2 = __hip_atomic_load(src + s0 + 2, __ATOMIC_RELAXED, __HIP_MEMORY_SCOPE_AGENT);
            q3 = __hip_atomic_load(src + s0 + 3, __ATOMIC_RELAXED, __HIP_MEMORY_SCOPE_AGENT);
            unsigned int bad = ((unsigned int)(q0 >> 32)) ^ want;
            bad |= ((unsigned int)(q1 >> 32)) ^ want;
            bad |= ((unsigned int)(q2 >> 32)) ^ want;
            bad |= ((unsigned int)(q3 >> 32)) ^ want;
            if (!bad) break;   // flag won the race to MALL — rare, just retry
        }
        h_lds[s0 + 0] = __uint_as_float((unsigned int)q0);
        h_lds[s0 + 1] = __uint_as_float((unsigned int)q1);
        h_lds[s0 + 2] = __uint_as_float((unsigned int)q2);
        h_lds[s0 + 3] = __uint_as_float((unsigned int)q3);

        // delayed ys store for step t-1 (ack hides under this whole step)
        if (i == 0 && t > 0) ys[(size_t)(t - 1) * Dh + col] = y_prev;

        __syncthreads();

        // ---- dot products from LDS against register weights ----
        float ar = 0.f, az = 0.f, an = 0.f;
        const float4* h4 = (const float4*)h_lds;
        #pragma unroll
        for (int j = 0; j < 8; ++j) {
            const float4 hv = h4[i + j * 32];
            ar += hv.x * wr[4*j] + hv.y * wr[4*j+1] + hv.z * wr[4*j+2] + hv.w * wr[4*j+3];
            az += hv.x * wz[4*j] + hv.y * wz[4*j+1] + hv.z * wz[4*j+2] + hv.w * wz[4*j+3];
            an += hv.x * wn[4*j] + hv.y * wn[4*j+1] + hv.z * wn[4*j+2] + hv.w * wn[4*j+3];
        }
        #pragma unroll
        for (int off = 16; off > 0; off >>= 1) {
            ar += __shfl_down(ar, off, 32);
            az += __shfl_down(az, off, 32);
            an += __shfl_down(an, off, 32);
        }

        if (i == 0) {
            const float r = fast_sigmoid(xr + ar);
            const float z = fast_sigmoid(xz + az);
            const float n = fast_tanh(xn + r * (an + bhn_c));
            const float hp = h_lds[col];
            const float hnew = (1.f - z) * n + z * hp;
            const unsigned long long packed =
                ((unsigned long long)(unsigned int)(t + 1) << 32) |
                (unsigned long long)__float_as_uint(hnew);
            __hip_atomic_store(dst + col, packed, __ATOMIC_RELAXED, __HIP_MEMORY_SCOPE_AGENT);
            y_prev = hnew;
        }
        __syncthreads();   // all 8 groups' publishes issued

        if (tid == 0)
            __hip_atomic_store(flags + b, (unsigned int)(t + 1),
                               __ATOMIC_RELAXED, __HIP_MEMORY_SCOPE_AGENT);

        // next step's xproj prefetch — fully off the wait path
        if (i == 0 && t + 1 < Tt) {
            const float* xp = xproj + (size_t)(t + 1) * (3 * Dh);
            xr_n = xp[col]; xz_n = xp[Dh + col]; xn_n = xp[2 * Dh + col];
        }
    }
    if (i == 0) ys[(size_t)(Tt - 1) * Dh + col] = y_prev;   // final delayed store
}

// ---------------------------------------------------------------------------
// In-place layernorm over rows of y [T][Dh], matching jnp mean/var, eps=1e-6
// ---------------------------------------------------------------------------
__global__ __launch_bounds__(256)
void layernorm_ip(float* __restrict__ y, const float* __restrict__ sc,
                  const float* __restrict__ bi)
{
    __shared__ float red[8], red2[8], stat[2];
    const int row = blockIdx.x, tid = threadIdx.x;
    float4* yr = (float4*)(y + (size_t)row * Dh);
    float4 v = yr[tid];
    float s  = v.x + v.y + v.z + v.w;
    float s2 = v.x*v.x + v.y*v.y + v.z*v.z + v.w*v.w;
    #pragma unroll
    for (int off = 32; off > 0; off >>= 1) {
        s  += __shfl_down(s,  off);
        s2 += __shfl_down(s2, off);
    }
    if ((tid & 63) == 0) { red[tid >> 6] = s; red2[tid >> 6] = s2; }
    __syncthreads();
    if (tid == 0) {
        float ts = 0.f, t2 = 0.f;
        #pragma unroll
        for (int w = 0; w < 4; ++w) { ts += red[w]; t2 += red2[w]; }
        const float mu  = ts / (float)Dh;
        const float var = t2 / (float)Dh - mu * mu;
        stat[0] = mu;
        stat[1] = rsqrtf(var + 1e-6f);
    }
    __syncthreads();
    const float mu = stat[0], rstd = stat[1];
    const float4 s4 = ((const float4*)sc)[tid];
    const float4 b4 = ((const float4*)bi)[tid];
    v.x = (v.x - mu) * rstd * s4.x + b4.x;
    v.y = (v.y - mu) * rstd * s4.y + b4.y;
    v.z = (v.z - mu) * rstd * s4.z + b4.z;
    v.w = (v.w - mu) * rstd * s4.w + b4.w;
    yr[tid] = v;
}

// ---------------------------------------------------------------------------
extern "C" void kernel_launch(void* const* d_in, const int* in_sizes, int n_in,
                              void* d_out, int out_size, void* d_ws, size_t ws_size,
                              hipStream_t stream)
{
    const float* xs   = (const float*)d_in[0];
    const float* h0   = (const float*)d_in[1];
    const float* Wir  = (const float*)d_in[2];
    const float* Wiz  = (const float*)d_in[3];
    const float* Win  = (const float*)d_in[4];
    const float* bir  = (const float*)d_in[5];
    const float* biz  = (const float*)d_in[6];
    const float* bin_ = (const float*)d_in[7];
    const float* Whr  = (const float*)d_in[8];
    const float* Whz  = (const float*)d_in[9];
    const float* Whn  = (const float*)d_in[10];
    const float* bhn  = (const float*)d_in[11];
    const float* Wl   = (const float*)d_in[12];
    const float* bl   = (const float*)d_in[13];
    const float* ln_s = (const float*)d_in[14];
    const float* ln_b = (const float*)d_in[15];
    float* out = (float*)d_out;

    // workspace layout
    float* xproj = (float*)d_ws;                               // T*3*Dh
    float* ys    = xproj + (size_t)Tt * 3 * Dh;                // T*Dh
    unsigned long long* hbuf = (unsigned long long*)(ys + (size_t)Tt * Dh); // 2*Dh packed
    unsigned int* flags = (unsigned int*)(hbuf + 2 * Dh);      // NB

    hipMemsetAsync(flags, 0, NB * sizeof(unsigned int), stream);

    // Phase 0: pack init state with tag 0 into buf[0]
    pack_h0<<<4, 256, 0, stream>>>(h0, hbuf);

    // Phase 1: input projections (bias folded in)
    dim3 ggrid(Dh / 64, Tt / 64);
    gemm64<false, false><<<ggrid, 256, 0, stream>>>(xs, Wir, bir, nullptr,
                                                    xproj + 0 * Dh, Tt, Dh, Dh, 3 * Dh);
    gemm64<false, false><<<ggrid, 256, 0, stream>>>(xs, Wiz, biz, nullptr,
                                                    xproj + 1 * Dh, Tt, Dh, Dh, 3 * Dh);
    gemm64<false, false><<<ggrid, 256, 0, stream>>>(xs, Win, bin_, nullptr,
                                                    xproj + 2 * Dh, Tt, Dh, Dh, 3 * Dh);

    // Phase 2: sequential scan (persistent, co-resident grid)
    gru_rec<<<NB, 256, 0, stream>>>(xproj, Whr, Whz, Whn, bhn, ys, hbuf, flags);

    // Phase 3: out = relu(ys) @ Wl + bl + xs, then in-place layernorm
    gemm64<true, true><<<ggrid, 256, 0, stream>>>(ys, Wl, bl, xs, out, Tt, Dh, Dh, Dh);
    layernorm_ip<<<Tt, 256, 0, stream>>>(out, ln_s, ln_b);
}

// Round 5
// 8111.878 us; speedup vs baseline: 2.1508x; 2.1508x over previous
//
#include <hip/hip_runtime.h>
#include <math.h>

#define Dh 1024
#define Tt 4096
#define NB 128   // recurrence blocks; each owns 8 output columns

// ---------------------------------------------------------------------------
// GEMM: C[M x N](ldc) = op(A[M x K]) @ B[K x N] + bias [+ resid]
// 64x64 tile, BK=16, 256 threads, 4x4 micro-tile per thread. fp32.
// ---------------------------------------------------------------------------
template<bool RELU, bool RESID>
__global__ __launch_bounds__(256)
void gemm64(const float* __restrict__ A, const float* __restrict__ B,
            const float* __restrict__ bias, const float* __restrict__ resid,
            float* __restrict__ C, int M, int N, int K, int ldc)
{
    __shared__ __align__(16) float As[16][68];   // [k][m], padded row
    __shared__ __align__(16) float Bs[16][64];   // [k][n]
    const int tid = threadIdx.x;
    const int tx = tid & 15, ty = tid >> 4;
    const int bn = blockIdx.x * 64, bm = blockIdx.y * 64;

    const int lm = tid >> 2, lk = (tid & 3) * 4;     // A tile load coords
    const int bk = tid >> 4, bn4 = (tid & 15) * 4;   // B tile load coords

    float acc[4][4] = {};

    for (int k0 = 0; k0 < K; k0 += 16) {
        float4 av = *(const float4*)(A + (size_t)(bm + lm) * K + k0 + lk);
        if (RELU) {
            av.x = fmaxf(av.x, 0.f); av.y = fmaxf(av.y, 0.f);
            av.z = fmaxf(av.z, 0.f); av.w = fmaxf(av.w, 0.f);
        }
        As[lk + 0][lm] = av.x; As[lk + 1][lm] = av.y;
        As[lk + 2][lm] = av.z; As[lk + 3][lm] = av.w;
        *(float4*)&Bs[bk][bn4] = *(const float4*)(B + (size_t)(k0 + bk) * N + bn + bn4);
        __syncthreads();
        #pragma unroll
        for (int kk = 0; kk < 16; ++kk) {
            float4 a4 = *(const float4*)&As[kk][ty * 4];
            float4 b4 = *(const float4*)&Bs[kk][tx * 4];
            acc[0][0] += a4.x * b4.x; acc[0][1] += a4.x * b4.y; acc[0][2] += a4.x * b4.z; acc[0][3] += a4.x * b4.w;
            acc[1][0] += a4.y * b4.x; acc[1][1] += a4.y * b4.y; acc[1][2] += a4.y * b4.z; acc[1][3] += a4.y * b4.w;
            acc[2][0] += a4.z * b4.x; acc[2][1] += a4.z * b4.y; acc[2][2] += a4.z * b4.z; acc[2][3] += a4.z * b4.w;
            acc[3][0] += a4.w * b4.x; acc[3][1] += a4.w * b4.y; acc[3][2] += a4.w * b4.z; acc[3][3] += a4.w * b4.w;
        }
        __syncthreads();
    }

    const float4 bias4 = *(const float4*)(bias + bn + tx * 4);
    #pragma unroll
    for (int i = 0; i < 4; ++i) {
        const int row = bm + ty * 4 + i;
        float4 o;
        o.x = acc[i][0] + bias4.x; o.y = acc[i][1] + bias4.y;
        o.z = acc[i][2] + bias4.z; o.w = acc[i][3] + bias4.w;
        if (RESID) {
            const float4 r4 = *(const float4*)(resid + (size_t)row * N + bn + tx * 4);
            o.x += r4.x; o.y += r4.y; o.z += r4.z; o.w += r4.w;
        }
        *(float4*)(C + (size_t)row * ldc + bn + tx * 4) = o;
    }
}

// ---------------------------------------------------------------------------
// Fast activations — tolerance is 0.099 absmax; native exp/rcp are ~1e-6 rel.
// ---------------------------------------------------------------------------
__device__ __forceinline__ float fast_sigmoid(float x)
{
    return __builtin_amdgcn_rcpf(1.f + __expf(-x));
}
__device__ __forceinline__ float fast_tanh(float x)
{
    x = fminf(15.f, fmaxf(-15.f, x));
    const float e2 = __expf(2.f * x);
    return (e2 - 1.f) * __builtin_amdgcn_rcpf(e2 + 1.f);
}

// ---------------------------------------------------------------------------
// Pack init_state into epoch-tagged slots: {tag=0 : value} in buf[0]
// ---------------------------------------------------------------------------
__global__ __launch_bounds__(256)
void pack_h0(const float* __restrict__ h0, unsigned long long* __restrict__ buf)
{
    const int idx = blockIdx.x * 256 + threadIdx.x;   // 0..1023
    __hip_atomic_store(buf + idx, (unsigned long long)__float_as_uint(h0[idx]),
                       __ATOMIC_RELAXED, __HIP_MEMORY_SCOPE_AGENT);
}

// ---------------------------------------------------------------------------
// Sequential GRU scan. 128 blocks x 320 threads (4 compute waves + 1 I/O
// wave), all co-resident. Block b owns columns [8b, 8b+8); one 32-lane group
// per column; weights register-resident (96 floats/thread).
//
// Single-hop sync (round-3 protocol): h entries are {tag,val} 64-bit slots;
// compute waves poll their 4 strided slots directly (poll IS the data read).
// Critical-path hygiene: compute waves issue NO global stores in steady
// state — wave 4 publishes the block's 8 slots (its store-acks drain while
// everyone else is polling), and the ys row store rotates across blocks
// (block t%NB writes row t-1 from poll registers, coalesced).
// ---------------------------------------------------------------------------
__global__ __launch_bounds__(320, 1)
void gru_rec(const float* __restrict__ xproj,   // [T][3*Dh]  (r,z,n) incl. input bias
             const float* __restrict__ Whr, const float* __restrict__ Whz,
             const float* __restrict__ Whn, const float* __restrict__ bhn,
             float* __restrict__ ys,            // [T][Dh]
             unsigned long long* __restrict__ hbuf)   // [2][Dh] packed {tag,val}
{
    const int b = blockIdx.x, tid = threadIdx.x;
    const bool is_compute = tid < 256;
    const int g = tid >> 5;        // group 0..7 -> local column (compute waves)
    const int i = tid & 31;        // lane in group
    const int col = b * 8 + g;

    __shared__ __align__(16) float h_lds[Dh];
    __shared__ float hnew_lds[8];

    // Register-resident weight slice: rows r = 4i + 128j + k
    float wr[32], wz[32], wn[32];
    float bhn_c = 0.f;
    if (is_compute) {
        #pragma unroll
        for (int j = 0; j < 8; ++j)
            #pragma unroll
            for (int k = 0; k < 4; ++k) {
                const int r = 4 * i + 128 * j + k;
                wr[j * 4 + k] = Whr[(size_t)r * Dh + col];
                wz[j * 4 + k] = Whz[(size_t)r * Dh + col];
                wn[j * 4 + k] = Whn[(size_t)r * Dh + col];
            }
        bhn_c = bhn[col];
    }

    // xproj prefetch registers (one step ahead)
    float xr_n = 0.f, xz_n = 0.f, xn_n = 0.f;
    if (is_compute && i == 0) {
        xr_n = xproj[col]; xz_n = xproj[Dh + col]; xn_n = xproj[2 * Dh + col];
    }

    for (int t = 0; t < Tt; ++t) {
        const unsigned long long* src = hbuf + (size_t)(t & 1) * Dh;
        unsigned long long*       dst = hbuf + (size_t)((t + 1) & 1) * Dh;
        const unsigned int want = (unsigned int)t;

        const float xr = xr_n, xz = xz_n, xn = xn_n;
        float v0 = 0.f, v1 = 0.f, v2 = 0.f, v3 = 0.f;

        if (is_compute) {
            // ---- single-hop poll: 4 strided slots, tag==t means valid ----
            unsigned long long p0, p1, p2, p3;
            int tries = 0;
            for (;;) {
                p0 = __hip_atomic_load(src + tid +   0, __ATOMIC_RELAXED, __HIP_MEMORY_SCOPE_AGENT);
                p1 = __hip_atomic_load(src + tid + 256, __ATOMIC_RELAXED, __HIP_MEMORY_SCOPE_AGENT);
                p2 = __hip_atomic_load(src + tid + 512, __ATOMIC_RELAXED, __HIP_MEMORY_SCOPE_AGENT);
                p3 = __hip_atomic_load(src + tid + 768, __ATOMIC_RELAXED, __HIP_MEMORY_SCOPE_AGENT);
                unsigned int bad = ((unsigned int)(p0 >> 32)) ^ want;
                bad |= ((unsigned int)(p1 >> 32)) ^ want;
                bad |= ((unsigned int)(p2 >> 32)) ^ want;
                bad |= ((unsigned int)(p3 >> 32)) ^ want;
                if (!bad) break;
                if (++tries > 6) __builtin_amdgcn_s_sleep(1);
            }
            v0 = __uint_as_float((unsigned int)p0);
            v1 = __uint_as_float((unsigned int)p1);
            v2 = __uint_as_float((unsigned int)p2);
            v3 = __uint_as_float((unsigned int)p3);
            h_lds[tid +   0] = v0;
            h_lds[tid + 256] = v1;
            h_lds[tid + 512] = v2;
            h_lds[tid + 768] = v3;
        }
        __syncthreads();                       // B1: h_lds complete

        if (is_compute) {
            // ---- dot products from LDS against register weights ----
            float ar = 0.f, az = 0.f, an = 0.f;
            const float4* h4 = (const float4*)h_lds;
            #pragma unroll
            for (int j = 0; j < 8; ++j) {
                const float4 hv = h4[i + j * 32];
                ar += hv.x * wr[4*j] + hv.y * wr[4*j+1] + hv.z * wr[4*j+2] + hv.w * wr[4*j+3];
                az += hv.x * wz[4*j] + hv.y * wz[4*j+1] + hv.z * wz[4*j+2] + hv.w * wz[4*j+3];
                an += hv.x * wn[4*j] + hv.y * wn[4*j+1] + hv.z * wn[4*j+2] + hv.w * wn[4*j+3];
            }
            #pragma unroll
            for (int off = 16; off > 0; off >>= 1) {
                ar += __shfl_down(ar, off, 32);
                az += __shfl_down(az, off, 32);
                an += __shfl_down(an, off, 32);
            }

            if (i == 0) {
                const float r = fast_sigmoid(xr + ar);
                const float z = fast_sigmoid(xz + az);
                const float n = fast_tanh(xn + r * (an + bhn_c));
                const float hp = h_lds[col];
                hnew_lds[g] = (1.f - z) * n + z * hp;   // hand off to I/O wave
            }
        }
        __syncthreads();                       // B2: hnew_lds complete

        if (!is_compute) {
            // ---- I/O wave publishes the block's 8 slots (1 cache line) ----
            const int lane = tid - 256;
            if (lane < 8) {
                const unsigned long long packed =
                    ((unsigned long long)(unsigned int)(t + 1) << 32) |
                    (unsigned long long)__float_as_uint(hnew_lds[lane]);
                __hip_atomic_store(dst + b * 8 + lane, packed,
                                   __ATOMIC_RELAXED, __HIP_MEMORY_SCOPE_AGENT);
            }
        } else {
            // rotating ys row store: block t%NB writes row t-1 from poll regs
            if (b == (t & (NB - 1)) && t > 0) {
                float* yrow = ys + (size_t)(t - 1) * Dh;
                yrow[tid +   0] = v0;
                yrow[tid + 256] = v1;
                yrow[tid + 512] = v2;
                yrow[tid + 768] = v3;
            }
            // next step's xproj prefetch — lands during publish+detect window
            if (i == 0 && t + 1 < Tt) {
                const float* xp = xproj + (size_t)(t + 1) * (3 * Dh);
                xr_n = xp[col]; xz_n = xp[Dh + col]; xn_n = xp[2 * Dh + col];
            }
        }
    }

    // final row: ys[Tt-1] = h_Tt (tag Tt lives in buffer Tt&1 = 0)
    if (b == (Tt & (NB - 1)) && is_compute) {
        const unsigned long long* src = hbuf + (size_t)(Tt & 1) * Dh;
        const unsigned int want = (unsigned int)Tt;
        unsigned long long p0, p1, p2, p3;
        for (;;) {
            p0 = __hip_atomic_load(src + tid +   0, __ATOMIC_RELAXED, __HIP_MEMORY_SCOPE_AGENT);
            p1 = __hip_atomic_load(src + tid + 256, __ATOMIC_RELAXED, __HIP_MEMORY_SCOPE_AGENT);
            p2 = __hip_atomic_load(src + tid + 512, __ATOMIC_RELAXED, __HIP_MEMORY_SCOPE_AGENT);
            p3 = __hip_atomic_load(src + tid + 768, __ATOMIC_RELAXED, __HIP_MEMORY_SCOPE_AGENT);
            unsigned int bad = ((unsigned int)(p0 >> 32)) ^ want;
            bad |= ((unsigned int)(p1 >> 32)) ^ want;
            bad |= ((unsigned int)(p2 >> 32)) ^ want;
            bad |= ((unsigned int)(p3 >> 32)) ^ want;
            if (!bad) break;
        }
        float* yrow = ys + (size_t)(Tt - 1) * Dh;
        yrow[tid +   0] = __uint_as_float((unsigned int)p0);
        yrow[tid + 256] = __uint_as_float((unsigned int)p1);
        yrow[tid + 512] = __uint_as_float((unsigned int)p2);
        yrow[tid + 768] = __uint_as_float((unsigned int)p3);
    }
}

// ---------------------------------------------------------------------------
// In-place layernorm over rows of y [T][Dh], matching jnp mean/var, eps=1e-6
// ---------------------------------------------------------------------------
__global__ __launch_bounds__(256)
void layernorm_ip(float* __restrict__ y, const float* __restrict__ sc,
                  const float* __restrict__ bi)
{
    __shared__ float red[8], red2[8], stat[2];
    const int row = blockIdx.x, tid = threadIdx.x;
    float4* yr = (float4*)(y + (size_t)row * Dh);
    float4 v = yr[tid];
    float s  = v.x + v.y + v.z + v.w;
    float s2 = v.x*v.x + v.y*v.y + v.z*v.z + v.w*v.w;
    #pragma unroll
    for (int off = 32; off > 0; off >>= 1) {
        s  += __shfl_down(s,  off);
        s2 += __shfl_down(s2, off);
    }
    if ((tid & 63) == 0) { red[tid >> 6] = s; red2[tid >> 6] = s2; }
    __syncthreads();
    if (tid == 0) {
        float ts = 0.f, t2 = 0.f;
        #pragma unroll
        for (int w = 0; w < 4; ++w) { ts += red[w]; t2 += red2[w]; }
        const float mu  = ts / (float)Dh;
        const float var = t2 / (float)Dh - mu * mu;
        stat[0] = mu;
        stat[1] = rsqrtf(var + 1e-6f);
    }
    __syncthreads();
    const float mu = stat[0], rstd = stat[1];
    const float4 s4 = ((const float4*)sc)[tid];
    const float4 b4 = ((const float4*)bi)[tid];
    v.x = (v.x - mu) * rstd * s4.x + b4.x;
    v.y = (v.y - mu) * rstd * s4.y + b4.y;
    v.z = (v.z - mu) * rstd * s4.z + b4.z;
    v.w = (v.w - mu) * rstd * s4.w + b4.w;
    yr[tid] = v;
}

// ---------------------------------------------------------------------------
extern "C" void kernel_launch(void* const* d_in, const int* in_sizes, int n_in,
                              void* d_out, int out_size, void* d_ws, size_t ws_size,
                              hipStream_t stream)
{
    const float* xs   = (const float*)d_in[0];
    const float* h0   = (const float*)d_in[1];
    const float* Wir  = (const float*)d_in[2];
    const float* Wiz  = (const float*)d_in[3];
    const float* Win  = (const float*)d_in[4];
    const float* bir  = (const float*)d_in[5];
    const float* biz  = (const float*)d_in[6];
    const float* bin_ = (const float*)d_in[7];
    const float* Whr  = (const float*)d_in[8];
    const float* Whz  = (const float*)d_in[9];
    const float* Whn  = (const float*)d_in[10];
    const float* bhn  = (const float*)d_in[11];
    const float* Wl   = (const float*)d_in[12];
    const float* bl   = (const float*)d_in[13];
    const float* ln_s = (const float*)d_in[14];
    const float* ln_b = (const float*)d_in[15];
    float* out = (float*)d_out;

    // workspace layout
    float* xproj = (float*)d_ws;                               // T*3*Dh
    float* ys    = xproj + (size_t)Tt * 3 * Dh;                // T*Dh
    unsigned long long* hbuf = (unsigned long long*)(ys + (size_t)Tt * Dh); // 2*Dh packed

    // Phase 0: pack init state with tag 0 into buf[0]
    pack_h0<<<4, 256, 0, stream>>>(h0, hbuf);

    // Phase 1: input projections (bias folded in)
    dim3 ggrid(Dh / 64, Tt / 64);
    gemm64<false, false><<<ggrid, 256, 0, stream>>>(xs, Wir, bir, nullptr,
                                                    xproj + 0 * Dh, Tt, Dh, Dh, 3 * Dh);
    gemm64<false, false><<<ggrid, 256, 0, stream>>>(xs, Wiz, biz, nullptr,
                                                    xproj + 1 * Dh, Tt, Dh, Dh, 3 * Dh);
    gemm64<false, false><<<ggrid, 256, 0, stream>>>(xs, Win, bin_, nullptr,
                                                    xproj + 2 * Dh, Tt, Dh, Dh, 3 * Dh);

    // Phase 2: sequential scan (persistent, co-resident grid)
    gru_rec<<<NB, 320, 0, stream>>>(xproj, Whr, Whz, Whn, bhn, ys, hbuf);

    // Phase 3: out = relu(ys) @ Wl + bl + xs, then in-place layernorm
    gemm64<true, true><<<ggrid, 256, 0, stream>>>(ys, Wl, bl, xs, out, Tt, Dh, Dh, Dh);
    layernorm_ip<<<Tt, 256, 0, stream>>>(out, ln_s, ln_b);
}